// Round 14
// baseline (65.023 us; speedup 1.0000x reference)
//
#include <hip/hip_runtime.h>
#include <math.h>

typedef unsigned int uint;
typedef unsigned long long ull;

#define L2E 1.44269504f

__device__ __forceinline__ float reluf(float z){ return fmaxf(z, 0.f); }
__device__ __forceinline__ float fexp(float z){ return __builtin_amdgcn_exp2f(z*L2E); }
__device__ __forceinline__ float frcp(float z){ return __builtin_amdgcn_rcpf(z); }
__device__ __forceinline__ float tanh_n(float z){
  return __fmaf_rn(2.f, __builtin_amdgcn_rcpf(1.f + __builtin_amdgcn_exp2f(-2.f*L2E*z)), -1.f);
}

// ===== ONE kernel, 512 blocks x 512 threads; 18 barriers (combines folded, reductions per-wave) =====
__global__ __launch_bounds__(512) void fused_kernel(
    const int* __restrict__ adj, const float* __restrict__ feat,
    const float* __restrict__ timei,
    const float* __restrict__ Weight, const float* __restrict__ Wv,
    const float* __restrict__ W1, const float* __restrict__ a1,
    const float* __restrict__ W2, const float* __restrict__ a2,
    const float* __restrict__ ipop,
    const float* __restrict__ wih0, const float* __restrict__ whh0,
    const float* __restrict__ bih0, const float* __restrict__ bhh0,
    const float* __restrict__ wih1, const float* __restrict__ whh1,
    const float* __restrict__ bih1, const float* __restrict__ bhh1,
    const float* __restrict__ mha_in_w, const float* __restrict__ mha_in_b,
    const float* __restrict__ mha_out_w, const float* __restrict__ mha_out_b,
    const float* __restrict__ fl1_w, const float* __restrict__ fl1_b,
    const float* __restrict__ fl2_w, const float* __restrict__ fl2_b,
    const float* __restrict__ fl3_w, const float* __restrict__ fl3_b,
    float* __restrict__ out)
{
  const int b = blockIdx.x, t = threadIdx.x;
  const int lane = t & 127, h = t >> 7;        // h in {0,1,2,3}
  const int wv = t >> 6, ln = t & 63;

  __shared__ ull   rowW[256];
  __shared__ float xs[128], tim[128], hm[128], eAs[128], rho_s[128], us[128];
  __shared__ float2 f2a[128];                  // {E1_i, Eh_i}
  __shared__ float  red1[4][128];              // pass partials (producer)
  __shared__ float2 red2f[4][128];             // second partial buffer
  __shared__ float4 pool4[4][128];
  __shared__ float2 kv[192];
  __shared__ float  hq[192], h2s[192];
  __shared__ float  pden[2][192], pnum[2][192];
  __shared__ float  cpart[8][2];
  __shared__ float  pqpart[8][16];
  __shared__ float  cons[24];                  // 2..9=P 10..17=Q 18..21=pA,qA,pB,qB
  __shared__ float  ips[64];

  // ================= region A (pre-B1) =================
  if (t < 128){ xs[t] = feat[b*128 + t]; tim[t] = timei[b*128 + t]; }

  float a2reg[16];
  if (t == 0){
    #pragma unroll
    for (int g = 0; g < 16; ++g) a2reg[g] = a2[g];
  }

  // LSTM prologue (thread 511 only)
  float h1v=0.f, c1s=0.f, h2v=0.f, c2s=0.f;
  float wi0s[4], wh0s[4], bb0s[4], wi1s[4], wh1s[4], bb1s[4];
  const float4* xsrc4 = (const float4*)(ipop + b*64);
  float4 xcur0, xcur1;
  if (t == 511){
    #pragma unroll
    for (int k = 0; k < 4; ++k){
      const float s = (k == 2) ? -2.f*L2E : -L2E;
      wi0s[k]=wih0[k]*s; wh0s[k]=whh0[k]*s; bb0s[k]=(bih0[k]+bhh0[k])*s;
      wi1s[k]=wih1[k]*s; wh1s[k]=whh1[k]*s; bb1s[k]=(bih1[k]+bhh1[k])*s;
    }
    xcur0 = xsrc4[0]; xcur1 = xsrc4[1];
  }
  auto lstm8 = [&](int c){
    if (t != 511) return;
    const float4 xa = xcur0, xb = xcur1;
    if (c < 7){ xcur0 = xsrc4[2*c+2]; xcur1 = xsrc4[2*c+3]; }
    float o[8];
    #pragma unroll
    for (int si = 0; si < 8; ++si){
      const float x = (si==0)?xa.x:(si==1)?xa.y:(si==2)?xa.z:(si==3)?xa.w:
                      (si==4)?xb.x:(si==5)?xb.y:(si==6)?xb.z:xb.w;
      float gi = frcp(1.f + __builtin_amdgcn_exp2f(__fmaf_rn(x, wi0s[0], __fmaf_rn(h1v, wh0s[0], bb0s[0]))));
      float gf = frcp(1.f + __builtin_amdgcn_exp2f(__fmaf_rn(x, wi0s[1], __fmaf_rn(h1v, wh0s[1], bb0s[1]))));
      float gg = __fmaf_rn(2.f, frcp(1.f + __builtin_amdgcn_exp2f(__fmaf_rn(x, wi0s[2], __fmaf_rn(h1v, wh0s[2], bb0s[2])))), -1.f);
      float go = frcp(1.f + __builtin_amdgcn_exp2f(__fmaf_rn(x, wi0s[3], __fmaf_rn(h1v, wh0s[3], bb0s[3]))));
      c1s = gf*c1s + gi*gg;  h1v = go*tanh_n(c1s);
      float hi = frcp(1.f + __builtin_amdgcn_exp2f(__fmaf_rn(h1v, wi1s[0], __fmaf_rn(h2v, wh1s[0], bb1s[0]))));
      float hf = frcp(1.f + __builtin_amdgcn_exp2f(__fmaf_rn(h1v, wi1s[1], __fmaf_rn(h2v, wh1s[1], bb1s[1]))));
      float hg = __fmaf_rn(2.f, frcp(1.f + __builtin_amdgcn_exp2f(__fmaf_rn(h1v, wi1s[2], __fmaf_rn(h2v, wh1s[2], bb1s[2])))), -1.f);
      float ho = frcp(1.f + __builtin_amdgcn_exp2f(__fmaf_rn(h1v, wi1s[3], __fmaf_rn(h2v, wh1s[3], bb1s[3])))) ;
      c2s = hf*c2s + hi*hg;  h2v = ho*tanh_n(c2s);
      o[si] = h2v;
    }
    #pragma unroll
    for (int si = 0; si < 8; ++si) ips[8*c + si] = o[si];
  };

  // ballot pack
  {
    const int* abase = adj + (((long)b) << 14) + wv*2048 + ln;
    ull myword = 0;
    #pragma unroll
    for (int blk = 0; blk < 4; ++blk){
      int v[8];
      #pragma unroll
      for (int q = 0; q < 8; ++q) v[q] = abase[(blk*8 + q)*64];
      #pragma unroll
      for (int q = 0; q < 8; ++q){
        ull m = __ballot(v[q] > 0);
        myword = (ln == blk*8 + q) ? m : myword;
      }
    }
    if (ln < 32) rowW[wv*32 + ln] = myword;
  }

  // consts partials
  {
    float w0 = W1[t];
    float s1 = w0*a1[t];
    float s2 = w0*a1[512+t];
    #pragma unroll
    for (int off = 32; off; off >>= 1){ s1 += __shfl_xor(s1, off); s2 += __shfl_xor(s2, off); }
    if (ln == 0){ cpart[wv][0] = s1; cpart[wv][1] = s2; }
  }
  {
    const float w = W1[t];
    const float wp = fmaxf(w, 0.f), wn = fminf(w, 0.f);
    const float4 A = *(const float4*)(W2 + t*8);
    const float4 Bv = *(const float4*)(W2 + t*8 + 4);
    float accP[8], accQ[8];
    accP[0]=wp*A.x;  accQ[0]=wn*A.x;   accP[1]=wp*A.y;  accQ[1]=wn*A.y;
    accP[2]=wp*A.z;  accQ[2]=wn*A.z;   accP[3]=wp*A.w;  accQ[3]=wn*A.w;
    accP[4]=wp*Bv.x; accQ[4]=wn*Bv.x;  accP[5]=wp*Bv.y; accQ[5]=wn*Bv.y;
    accP[6]=wp*Bv.z; accQ[6]=wn*Bv.z;  accP[7]=wp*Bv.w; accQ[7]=wn*Bv.w;
    #pragma unroll
    for (int g = 0; g < 8; ++g){
      float p = accP[g], q = accQ[g];
      #pragma unroll
      for (int off = 32; off; off >>= 1){ p += __shfl_xor(p, off); q += __shfl_xor(q, off); }
      if (ln == 0){ pqpart[wv][g] = p; pqpart[wv][8+g] = q; }
    }
  }
  __syncthreads();   // B1

  // ===== P2: colm transpose (all) + redundant c1/c2/rmax + GAT1 factors + t0 cons =====
  const uint rowm = (uint)(rowW[lane*2 + (h>>1)] >> ((h&1)*32));
  uint colm = 0;
  {
    const int wsel = lane >> 6, bsel = lane & 63;
    #pragma unroll
    for (int k = 0; k < 32; ++k)
      colm |= (uint)((rowW[(32*h + k)*2 + wsel] >> bsel) & 1ull) << k;
  }
  float c1r = 0.f, c2r = 0.f;
  #pragma unroll
  for (int wvi = 0; wvi < 8; ++wvi){ c1r += cpart[wvi][0]; c2r += cpart[wvi][1]; }
  float wmx, wmn;
  {
    float mx = fmaxf(xs[ln], xs[ln+64]);
    float mn = fminf(xs[ln], xs[ln+64]);
    #pragma unroll
    for (int off = 32; off; off >>= 1){
      mx = fmaxf(mx, __shfl_xor(mx, off));
      mn = fminf(mn, __shfl_xor(mn, off));
    }
    wmx = mx; wmn = mn;
  }
  float myE1=0.f, myRho=0.f, myx=0.f;
  {
    const float rmax = (c1r >= 0.f) ? c1r*wmx : c1r*wmn;
    if (t < 128){
      myx = xs[t];
      float r  = c1r*myx;
      float cj = c2r*myx;
      float d  = r - rmax;
      myE1 = fexp(d);
      float Eh = fexp(0.5f*d);
      myRho = fexp(-0.5f*fmaxf(rmax + cj, -170.f));
      f2a[t] = make_float2(myE1, Eh);
      rho_s[t] = myRho;
    }
  }
  if (t == 0){
    float pAx=0.f, qAx=0.f, pBx=0.f, qBx=0.f;
    #pragma unroll
    for (int g = 0; g < 8; ++g){
      float P = 0.f, Q = 0.f;
      #pragma unroll
      for (int wvi = 0; wvi < 8; ++wvi){ P += pqpart[wvi][g]; Q += pqpart[wvi][8+g]; }
      cons[2+g] = P; cons[10+g] = Q;
      pAx = __fmaf_rn(P, a2reg[g],   pAx);  qAx = __fmaf_rn(Q, a2reg[g],   qAx);
      pBx = __fmaf_rn(P, a2reg[8+g], pBx);  qBx = __fmaf_rn(Q, a2reg[8+g], qBx);
    }
    cons[18]=pAx; cons[19]=qAx; cons[20]=pBx; cons[21]=qBx;
  }
  lstm8(0);
  __syncthreads();   // B2

  // ===== P3: GAT1 col pass =====
  {
    const float rho = rho_s[lane];
    float s = 0.f;
    #pragma unroll
    for (int k = 0; k < 32; ++k){
      float2 E = f2a[32*h + k];
      float v = fmaxf(E.x, rho*E.y);
      s += ((colm >> k) & 1u) ? v : 0.f;
    }
    red1[h][lane] = s;
  }
  lstm8(1);
  __syncthreads();   // B3

  // ===== P4: GAT1 row pass with inline combine =====
  {
    const float om = frcp(f2a[lane].y);
    float acc = 0.f;
    #pragma unroll 8
    for (int k = 0; k < 32; ++k){
      int j = 32*h + k;
      float s = red1[0][j] + red1[1][j] + red1[2][j] + red1[3][j];
      float sinv = frcp(s);
      float xj = xs[j];
      float ax = fabsf(xj)*sinv;
      float v = fmaxf(ax, om*(rho_s[j]*ax));
      float sg = ((rowm >> k) & 1u) ? ((xj >= 0.f) ? 1.f : -1.f) : 0.f;
      acc = __fmaf_rn(v, sg, acc);
    }
    red2f[h][lane].x = acc;
  }
  lstm8(2);
  __syncthreads();   // B4

  // ===== P5: u, eAs, us (t<128) =====
  float u = 0.f, eBv = 0.f, eAv = 0.f;
  if (t < 128){
    u = myE1*(red2f[0][t].x + red2f[1][t].x + red2f[2][t].x + red2f[3][t].x);
    eAv = (u >= 0.f ? cons[18] : cons[19])*u;
    eBv = (u >= 0.f ? cons[20] : cons[21])*u;
    eAs[t] = eAv;
    us[t] = u;
  }
  lstm8(3);
  __syncthreads();   // B5

  // ===== P6: GAT2 factors (eAmax per-wave redundant) =====
  float myE1b=0.f;
  {
    float mx = fmaxf(eAs[ln], eAs[ln+64]);
    #pragma unroll
    for (int off = 32; off; off >>= 1) mx = fmaxf(mx, __shfl_xor(mx, off));
    const float eAmax = mx;
    if (t < 128){
      float d2 = eAv - eAmax;
      myE1b = fexp(d2);
      float Ehb = fexp(0.5f*d2);
      float rho2 = fexp(-0.5f*fmaxf(eAmax + eBv, -170.f));
      f2a[t] = make_float2(myE1b, Ehb);
      rho_s[t] = rho2;
    }
  }
  lstm8(4);
  __syncthreads();   // B6

  // ===== P7: GAT2 col pass =====
  {
    const float rho = rho_s[lane];
    float s = 0.f;
    #pragma unroll
    for (int k = 0; k < 32; ++k){
      float2 E = f2a[32*h + k];
      float v = fmaxf(E.x, rho*E.y);
      s += ((colm >> k) & 1u) ? v : 0.f;
    }
    red1[h][lane] = s;
  }
  lstm8(5);
  __syncthreads();   // B7

  // ===== P8: GAT2 row pass with inline combine =====
  {
    const float om = frcp(f2a[lane].y);
    float accp = 0.f, accn = 0.f;
    #pragma unroll 8
    for (int k = 0; k < 32; ++k){
      int j = 32*h + k;
      float s = red1[0][j] + red1[1][j] + red1[2][j] + red1[3][j];
      float sinv = frcp(s);
      float uj = us[j];
      float rho2j = rho_s[j];
      float up = fmaxf(uj, 0.f)*sinv, un = -fminf(uj, 0.f)*sinv;
      float v1 = fmaxf(up, om*(rho2j*up));
      float v2 = fmaxf(un, om*(rho2j*un));
      bool m = ((rowm >> k) & 1u);
      accp += m ? v1 : 0.f;
      accn += m ? v2 : 0.f;
    }
    red2f[h][lane] = make_float2(accp, accn);
  }
  lstm8(6);
  __syncthreads();   // B8

  // ===== P9: hm (t<128) =====
  if (t < 128){
    float ap=0.f, an=0.f;
    #pragma unroll
    for (int g = 0; g < 4; ++g){ float2 v = red2f[g][t]; ap += v.x; an += v.y; }
    float sp = myE1b*ap, sn = -myE1b*an;
    float acc = 0.f;
    #pragma unroll
    for (int g = 0; g < 8; ++g) acc += reluf(__fmaf_rn(sp, cons[2+g], sn*cons[10+g]));
    hm[t] = 0.125f*acc;
  }
  lstm8(7);
  __syncthreads();   // B9

  // ===== P10: attention pooling =====
  {
    const int n = lane;
    float a0=0.f, a1v=0.f, v0=0.f, v1=0.f;
    const int m0 = h*32;
    #pragma unroll 8
    for (int k = 0; k < 32; ++k){
      int m = m0 + k;
      float hmv = hm[m], tv = tim[m];
      float wg = Weight[(m<<7) + n], wvv = Wv[(m<<7) + n];
      a0 = __fmaf_rn(hmv, wg, a0); a1v = __fmaf_rn(tv, wg, a1v);
      v0 = __fmaf_rn(hmv, wvv, v0); v1 = __fmaf_rn(tv, wvv, v1);
    }
    pool4[h][n] = make_float4(a0, a1v, v0, v1);
  }
  __syncthreads();   // B10

  // ===== P11: A/V combine + att (t<128) =====
  float att0 = 0.f, att1 = 0.f, rsv = 0.f;
  if (t < 128){
    float A0=0.f, A1=0.f, V0=0.f, V1=0.f;
    #pragma unroll
    for (int g = 0; g < 4; ++g){ float4 v = pool4[g][t]; A0+=v.x; A1+=v.y; V0+=v.z; V1+=v.w; }
    red2f[0][t] = make_float2(V0, V1);
    float mx = fmaxf(A0, A1);
    att0 = fexp(A0 - mx); att1 = fexp(A1 - mx);
    rsv = frcp(att0 + att1);
  }
  __syncthreads();   // B11

  // ===== P12: hq (t<128) + ips copy =====
  if (t < 128){
    float r0, r1;
    if (t < 64){ r0 = red2f[0][2*t].x;     r1 = red2f[0][2*t+1].x; }
    else       { r0 = red2f[0][2*t-128].y; r1 = red2f[0][2*t-127].y; }
    hq[t] = (reluf(r0)*att0 + reluf(r1)*att1)*rsv;
  }
  if (t >= 192 && t < 256) hq[128 + (t - 192)] = ips[t - 192];
  __syncthreads();   // B12

  // ===== P13: kv =====
  const float wq = mha_in_w[0], wk = mha_in_w[1], wvv_ = mha_in_w[2];
  const float bq = mha_in_b[0], bk = mha_in_b[1], bv = mha_in_b[2];
  const float wo = mha_out_w[0], bo = mha_out_b[0];
  if (t < 192){
    float hv_ = hq[t];
    kv[t] = make_float2(__fmaf_rn(hv_, wk, bk), __fmaf_rn(hv_, wvv_, bv));
  }
  __syncthreads();   // B13

  // ===== P14: MHA partials (kmax/kmin per-wave redundant) =====
  {
    float k0 = kv[ln].x, k1 = kv[ln+64].x, k2 = kv[ln+128].x;
    float mx = fmaxf(fmaxf(k0, k1), k2);
    float mn = fminf(fminf(k0, k1), k2);
    #pragma unroll
    for (int off = 32; off; off >>= 1){
      mx = fmaxf(mx, __shfl_xor(mx, off));
      mn = fminf(mn, __shfl_xor(mn, off));
    }
    if (t < 384){
      const int half = (t >= 192), tt = t - half*192;
      float qi = __fmaf_rn(hq[tt], wq, bq);
      float mxx = (qi >= 0.f) ? qi*mx : qi*mn;
      const float qi2 = qi*L2E, mx2 = mxx*L2E;
      float den = 0.f, num = 0.f;
      const int j0 = half*96;
      #pragma unroll 8
      for (int jj = 0; jj < 96; ++jj){
        float2 K = kv[j0 + jj];
        float e = __builtin_amdgcn_exp2f(__fmaf_rn(qi2, K.x, -mx2));
        den += e; num = __fmaf_rn(e, K.y, num);
      }
      pden[half][tt] = den; pnum[half][tt] = num;
    }
  }
  __syncthreads();   // B14

  // ===== P15: h2s =====
  if (t < 192){
    float den = pden[0][t] + pden[1][t];
    float num = pnum[0][t] + pnum[1][t];
    h2s[t] = __fmaf_rn(num*frcp(den), wo, bo) + hq[t];
  }
  __syncthreads();   // B15

  // ===== P16: fl1 partials =====
  {
    const int n = t & 127, qtr = t >> 7;
    float acc = 0.f;
    const int i0 = qtr*48;
    #pragma unroll 8
    for (int k = 0; k < 48; ++k){
      int i = i0 + k;
      acc = __fmaf_rn(h2s[i], fl1_w[i*128 + n], acc);
    }
    red1[qtr][n] = acc;
  }
  __syncthreads();   // B16

  // ===== P17: fl1 combine =====
  if (t < 128) rho_s[t] = reluf(red1[0][t] + red1[1][t] + red1[2][t] + red1[3][t] + fl1_b[t]);
  __syncthreads();   // B17

  // ===== P18: fl2 partials =====
  if (t < 128){
    const int n = t & 31, seg = t >> 5;
    float p = 0.f;
    #pragma unroll 8
    for (int k = 0; k < 32; ++k){
      int i = seg*32 + k;
      p = __fmaf_rn(rho_s[i], fl2_w[i*32 + n], p);
    }
    red1[seg][n] = p;
  }
  __syncthreads();   // B18

  // ===== P19: fl2 combine + tanh + fl3, all inside wave 0 =====
  if (t < 64){
    float p = 0.f;
    if (t < 32){
      float s = red1[0][t] + red1[1][t] + red1[2][t] + red1[3][t] + fl2_b[t];
      p = tanh_n(s)*fl3_w[t];
    }
    #pragma unroll
    for (int off = 32; off; off >>= 1) p += __shfl_xor(p, off);
    if (t == 0) out[b] = reluf(p + fl3_b[0]);
  }
}

extern "C" void kernel_launch(void* const* d_in, const int* in_sizes, int n_in,
                              void* d_out, int out_size, void* d_ws, size_t ws_size,
                              hipStream_t stream) {
  const int*   adj    = (const int*)  d_in[0];
  const float* feat   = (const float*)d_in[1];
  const float* timei  = (const float*)d_in[2];
  const float* ipop   = (const float*)d_in[3];
  const float* W1     = (const float*)d_in[4];
  const float* a1     = (const float*)d_in[5];
  const float* W2     = (const float*)d_in[6];
  const float* a2     = (const float*)d_in[7];
  const float* Weight = (const float*)d_in[8];
  const float* Wv     = (const float*)d_in[9];
  const float* wih0   = (const float*)d_in[10];
  const float* whh0   = (const float*)d_in[11];
  const float* bih0   = (const float*)d_in[12];
  const float* bhh0   = (const float*)d_in[13];
  const float* wih1   = (const float*)d_in[14];
  const float* whh1   = (const float*)d_in[15];
  const float* bih1   = (const float*)d_in[16];
  const float* bhh1   = (const float*)d_in[17];
  const float* mha_in_w  = (const float*)d_in[18];
  const float* mha_in_b  = (const float*)d_in[19];
  const float* mha_out_w = (const float*)d_in[20];
  const float* mha_out_b = (const float*)d_in[21];
  const float* fl1_w = (const float*)d_in[22];
  const float* fl1_b = (const float*)d_in[23];
  const float* fl2_w = (const float*)d_in[24];
  const float* fl2_b = (const float*)d_in[25];
  const float* fl3_w = (const float*)d_in[26];
  const float* fl3_b = (const float*)d_in[27];

  fused_kernel<<<512, 512, 0, stream>>>(adj, feat, timei, Weight, Wv,
                                        W1, a1, W2, a2, ipop,
                                        wih0, whh0, bih0, bhh0,
                                        wih1, whh1, bih1, bhh1,
                                        mha_in_w, mha_in_b, mha_out_w, mha_out_b,
                                        fl1_w, fl1_b, fl2_w, fl2_b, fl3_w, fl3_b,
                                        (float*)d_out);
}

// Round 15
// 61.452 us; speedup vs baseline: 1.0581x; 1.0581x over previous
//
#include <hip/hip_runtime.h>
#include <math.h>

typedef unsigned int uint;
typedef unsigned long long ull;

#define L2E 1.44269504f

__device__ __forceinline__ float reluf(float z){ return fmaxf(z, 0.f); }
__device__ __forceinline__ float fexp(float z){ return __builtin_amdgcn_exp2f(z*L2E); }
__device__ __forceinline__ float frcp(float z){ return __builtin_amdgcn_rcpf(z); }
__device__ __forceinline__ float tanh_n(float z){
  return __fmaf_rn(2.f, __builtin_amdgcn_rcpf(1.f + __builtin_amdgcn_exp2f(-2.f*L2E*z)), -1.f);
}

// ===== ONE kernel, 512 blocks x 512 threads; r11 structure, 21 barriers (3 safe merges) =====
__global__ __launch_bounds__(512) void fused_kernel(
    const int* __restrict__ adj, const float* __restrict__ feat,
    const float* __restrict__ timei,
    const float* __restrict__ Weight, const float* __restrict__ Wv,
    const float* __restrict__ W1, const float* __restrict__ a1,
    const float* __restrict__ W2, const float* __restrict__ a2,
    const float* __restrict__ ipop,
    const float* __restrict__ wih0, const float* __restrict__ whh0,
    const float* __restrict__ bih0, const float* __restrict__ bhh0,
    const float* __restrict__ wih1, const float* __restrict__ whh1,
    const float* __restrict__ bih1, const float* __restrict__ bhh1,
    const float* __restrict__ mha_in_w, const float* __restrict__ mha_in_b,
    const float* __restrict__ mha_out_w, const float* __restrict__ mha_out_b,
    const float* __restrict__ fl1_w, const float* __restrict__ fl1_b,
    const float* __restrict__ fl2_w, const float* __restrict__ fl2_b,
    const float* __restrict__ fl3_w, const float* __restrict__ fl3_b,
    float* __restrict__ out)
{
  const int b = blockIdx.x, t = threadIdx.x;
  const int lane = t & 127, h = t >> 7;        // h in {0,1,2,3}
  const int wv = t >> 6, ln = t & 63;

  __shared__ ull   rowW[256];
  __shared__ float xs[128], tim[128], hm[128], eAs[128], rho_s[128], us[128];
  __shared__ float2 f2a[128];                  // {E1_i, Eh_i}
  __shared__ float  red1[4][128];
  __shared__ float2 red4[4][128];
  __shared__ float4 q4[128];
  __shared__ float4 pool4[4][128];
  __shared__ float2 kv[192];
  __shared__ float  hq[192], h2s[192];
  __shared__ float  pden[2][192], pnum[2][192];
  __shared__ float  sred[8];
  __shared__ float  cpart[8][2];
  __shared__ float  pqpart[8][16];
  __shared__ float  cons[24];
  __shared__ float  ips[64];

  // ================= region A (pre-B1) =================
  if (t < 128){ xs[t] = feat[b*128 + t]; tim[t] = timei[b*128 + t]; }

  float a2reg[16];
  if (t == 0){
    #pragma unroll
    for (int g = 0; g < 16; ++g) a2reg[g] = a2[g];
  }

  // LSTM prologue (thread 511 only)
  float h1v=0.f, c1s=0.f, h2v=0.f, c2s=0.f;
  float wi0s[4], wh0s[4], bb0s[4], wi1s[4], wh1s[4], bb1s[4];
  const float4* xsrc4 = (const float4*)(ipop + b*64);
  float4 xcur0, xcur1;
  if (t == 511){
    #pragma unroll
    for (int k = 0; k < 4; ++k){
      const float s = (k == 2) ? -2.f*L2E : -L2E;
      wi0s[k]=wih0[k]*s; wh0s[k]=whh0[k]*s; bb0s[k]=(bih0[k]+bhh0[k])*s;
      wi1s[k]=wih1[k]*s; wh1s[k]=whh1[k]*s; bb1s[k]=(bih1[k]+bhh1[k])*s;
    }
    xcur0 = xsrc4[0]; xcur1 = xsrc4[1];
  }
  auto lstm8 = [&](int c){
    if (t != 511) return;
    const float4 xa = xcur0, xb = xcur1;
    if (c < 7){ xcur0 = xsrc4[2*c+2]; xcur1 = xsrc4[2*c+3]; }
    float o[8];
    #pragma unroll
    for (int si = 0; si < 8; ++si){
      const float x = (si==0)?xa.x:(si==1)?xa.y:(si==2)?xa.z:(si==3)?xa.w:
                      (si==4)?xb.x:(si==5)?xb.y:(si==6)?xb.z:xb.w;
      float gi = frcp(1.f + __builtin_amdgcn_exp2f(__fmaf_rn(x, wi0s[0], __fmaf_rn(h1v, wh0s[0], bb0s[0]))));
      float gf = frcp(1.f + __builtin_amdgcn_exp2f(__fmaf_rn(x, wi0s[1], __fmaf_rn(h1v, wh0s[1], bb0s[1]))));
      float gg = __fmaf_rn(2.f, frcp(1.f + __builtin_amdgcn_exp2f(__fmaf_rn(x, wi0s[2], __fmaf_rn(h1v, wh0s[2], bb0s[2])))), -1.f);
      float go = frcp(1.f + __builtin_amdgcn_exp2f(__fmaf_rn(x, wi0s[3], __fmaf_rn(h1v, wh0s[3], bb0s[3]))));
      c1s = gf*c1s + gi*gg;  h1v = go*tanh_n(c1s);
      float hi = frcp(1.f + __builtin_amdgcn_exp2f(__fmaf_rn(h1v, wi1s[0], __fmaf_rn(h2v, wh1s[0], bb1s[0]))));
      float hf = frcp(1.f + __builtin_amdgcn_exp2f(__fmaf_rn(h1v, wi1s[1], __fmaf_rn(h2v, wh1s[1], bb1s[1]))));
      float hg = __fmaf_rn(2.f, frcp(1.f + __builtin_amdgcn_exp2f(__fmaf_rn(h1v, wi1s[2], __fmaf_rn(h2v, wh1s[2], bb1s[2])))), -1.f);
      float ho = frcp(1.f + __builtin_amdgcn_exp2f(__fmaf_rn(h1v, wi1s[3], __fmaf_rn(h2v, wh1s[3], bb1s[3])))) ;
      c2s = hf*c2s + hi*hg;  h2v = ho*tanh_n(c2s);
      o[si] = h2v;
    }
    #pragma unroll
    for (int si = 0; si < 8; ++si) ips[8*c + si] = o[si];
  };

  // ballot pack
  {
    const int* abase = adj + (((long)b) << 14) + wv*2048 + ln;
    ull myword = 0;
    #pragma unroll
    for (int blk = 0; blk < 4; ++blk){
      int v[8];
      #pragma unroll
      for (int q = 0; q < 8; ++q) v[q] = abase[(blk*8 + q)*64];
      #pragma unroll
      for (int q = 0; q < 8; ++q){
        ull m = __ballot(v[q] > 0);
        myword = (ln == blk*8 + q) ? m : myword;
      }
    }
    if (ln < 32) rowW[wv*32 + ln] = myword;
  }

  // consts partials
  {
    float w0 = W1[t];
    float s1 = w0*a1[t];
    float s2 = w0*a1[512+t];
    #pragma unroll
    for (int off = 32; off; off >>= 1){ s1 += __shfl_xor(s1, off); s2 += __shfl_xor(s2, off); }
    if (ln == 0){ cpart[wv][0] = s1; cpart[wv][1] = s2; }
  }
  {
    const float w = W1[t];
    const float wp = fmaxf(w, 0.f), wn = fminf(w, 0.f);
    const float4 A = *(const float4*)(W2 + t*8);
    const float4 Bv = *(const float4*)(W2 + t*8 + 4);
    float accP[8], accQ[8];
    accP[0]=wp*A.x;  accQ[0]=wn*A.x;   accP[1]=wp*A.y;  accQ[1]=wn*A.y;
    accP[2]=wp*A.z;  accQ[2]=wn*A.z;   accP[3]=wp*A.w;  accQ[3]=wn*A.w;
    accP[4]=wp*Bv.x; accQ[4]=wn*Bv.x;  accP[5]=wp*Bv.y; accQ[5]=wn*Bv.y;
    accP[6]=wp*Bv.z; accQ[6]=wn*Bv.z;  accP[7]=wp*Bv.w; accQ[7]=wn*Bv.w;
    #pragma unroll
    for (int g = 0; g < 8; ++g){
      float p = accP[g], q = accQ[g];
      #pragma unroll
      for (int off = 32; off; off >>= 1){ p += __shfl_xor(p, off); q += __shfl_xor(q, off); }
      if (ln == 0){ pqpart[wv][g] = p; pqpart[wv][8+g] = q; }
    }
  }
  __syncthreads();   // B1

  // ===== P2: transpose + xs-minmax + t0 cons =====
  const uint rowm = (uint)(rowW[lane*2 + (h>>1)] >> ((h&1)*32));
  uint colm = 0;
  {
    const int wsel = lane >> 6, bsel = lane & 63;
    #pragma unroll
    for (int k = 0; k < 32; ++k)
      colm |= (uint)((rowW[(32*h + k)*2 + wsel] >> bsel) & 1ull) << k;
  }
  if (t < 64){
    float mx = fmaxf(xs[t], xs[t+64]);
    float mn = fminf(xs[t], xs[t+64]);
    #pragma unroll
    for (int off = 32; off; off >>= 1){
      mx = fmaxf(mx, __shfl_xor(mx, off));
      mn = fminf(mn, __shfl_xor(mn, off));
    }
    if (t == 0){ sred[0] = mx; sred[1] = mn; }
  }
  if (t == 0){
    float c1v = 0.f, c2v = 0.f;
    #pragma unroll
    for (int wvi = 0; wvi < 8; ++wvi){ c1v += cpart[wvi][0]; c2v += cpart[wvi][1]; }
    cons[0] = c1v; cons[1] = c2v;
    float pAx=0.f, qAx=0.f, pBx=0.f, qBx=0.f;
    #pragma unroll
    for (int g = 0; g < 8; ++g){
      float P = 0.f, Q = 0.f;
      #pragma unroll
      for (int wvi = 0; wvi < 8; ++wvi){ P += pqpart[wvi][g]; Q += pqpart[wvi][8+g]; }
      cons[2+g] = P; cons[10+g] = Q;
      pAx = __fmaf_rn(P, a2reg[g],   pAx);  qAx = __fmaf_rn(Q, a2reg[g],   qAx);
      pBx = __fmaf_rn(P, a2reg[8+g], pBx);  qBx = __fmaf_rn(Q, a2reg[8+g], qBx);
    }
    cons[18]=pAx; cons[19]=qAx; cons[20]=pBx; cons[21]=qBx;
  }
  lstm8(0);
  __syncthreads();   // B2

  // ===== P3: GAT1 factors =====
  float myE1=0.f, myRho=0.f, myx=0.f;
  {
    const float c1 = cons[0], c2 = cons[1];
    const float rmax = (c1 >= 0.f) ? c1*sred[0] : c1*sred[1];
    if (t < 128){
      myx = xs[t];
      float r  = c1*myx;
      float cj = c2*myx;
      float d  = r - rmax;
      myE1 = fexp(d);
      float Eh = fexp(0.5f*d);
      myRho = fexp(-0.5f*fmaxf(rmax + cj, -170.f));
      f2a[t] = make_float2(myE1, Eh);
      rho_s[t] = myRho;
    }
  }
  lstm8(1);
  __syncthreads();   // B3

  // ===== P4: GAT1 col pass =====
  {
    const float rho = rho_s[lane];
    float s = 0.f;
    #pragma unroll
    for (int k = 0; k < 32; ++k){
      float2 E = f2a[32*h + k];
      float v = fmaxf(E.x, rho*E.y);
      s += ((colm >> k) & 1u) ? v : 0.f;
    }
    red1[h][lane] = s;
  }
  lstm8(2);
  __syncthreads();   // B4

  // ===== P5: combine -> q4 =====
  if (t < 128){
    float s = red1[0][t] + red1[1][t] + red1[2][t] + red1[3][t];
    float sinv = frcp(s);
    float ax = fabsf(myx)*sinv;
    q4[t] = make_float4(ax, myRho*ax, (myx >= 0.f) ? 1.f : -1.f, 0.f);
  }
  lstm8(3);
  __syncthreads();   // B5

  // ===== P6: GAT1 row pass =====
  {
    const float om = frcp(f2a[lane].y);
    float acc = 0.f;
    #pragma unroll
    for (int k = 0; k < 32; ++k){
      float4 G = q4[32*h + k];
      float v = fmaxf(G.x, om*G.y);
      float sg = ((rowm >> k) & 1u) ? G.z : 0.f;
      acc = __fmaf_rn(v, sg, acc);
    }
    red1[h][lane] = acc;
  }
  lstm8(4);
  __syncthreads();   // B6

  // ===== P7: u, eAs, us =====
  float u = 0.f, eBv = 0.f, eAv = 0.f;
  if (t < 128){
    u = myE1*(red1[0][t] + red1[1][t] + red1[2][t] + red1[3][t]);
    eAv = (u >= 0.f ? cons[18] : cons[19])*u;
    eBv = (u >= 0.f ? cons[20] : cons[21])*u;
    eAs[t] = eAv;
    us[t] = u;
  }
  lstm8(5);
  __syncthreads();   // B7

  // ===== P8: GAT2 factors + redundant eAmax (merged; same op order as r11 reduce) =====
  float myE1b=0.f;
  if (t < 128){
    float mx = fmaxf(eAs[ln], eAs[ln+64]);
    #pragma unroll
    for (int off = 32; off; off >>= 1) mx = fmaxf(mx, __shfl_xor(mx, off));
    const float eAmax = mx;
    float d2 = eAv - eAmax;
    myE1b = fexp(d2);
    float Ehb = fexp(0.5f*d2);
    float rho2 = fexp(-0.5f*fmaxf(eAmax + eBv, -170.f));
    f2a[t] = make_float2(myE1b, Ehb);
    rho_s[t] = rho2;
  }
  lstm8(6);
  __syncthreads();   // B8

  // ===== P9: GAT2 col pass =====
  {
    const float rho = rho_s[lane];
    float s = 0.f;
    #pragma unroll
    for (int k = 0; k < 32; ++k){
      float2 E = f2a[32*h + k];
      float v = fmaxf(E.x, rho*E.y);
      s += ((colm >> k) & 1u) ? v : 0.f;
    }
    red1[h][lane] = s;
  }
  lstm8(7);
  __syncthreads();   // B9

  // ===== P10: combine -> q4 =====
  if (t < 128){
    float s = red1[0][t] + red1[1][t] + red1[2][t] + red1[3][t];
    float sinv = frcp(s);
    float rho2 = rho_s[t];
    float up = fmaxf(u, 0.f)*sinv, un = -fminf(u, 0.f)*sinv;
    q4[t] = make_float4(up, rho2*up, un, rho2*un);
  }
  __syncthreads();   // B10

  // ===== P11: GAT2 row pass =====
  {
    const float om = frcp(f2a[lane].y);
    float accp = 0.f, accn = 0.f;
    #pragma unroll
    for (int k = 0; k < 32; ++k){
      float4 G = q4[32*h + k];
      bool m = ((rowm >> k) & 1u);
      float v1 = fmaxf(G.x, om*G.y);
      float v2 = fmaxf(G.z, om*G.w);
      accp += m ? v1 : 0.f;
      accn += m ? v2 : 0.f;
    }
    red4[h][lane] = make_float2(accp, accn);
  }
  __syncthreads();   // B11

  // ===== P12: hm =====
  if (t < 128){
    float ap=0.f, an=0.f;
    #pragma unroll
    for (int g = 0; g < 4; ++g){ float2 v = red4[g][t]; ap += v.x; an += v.y; }
    float sp = myE1b*ap, sn = -myE1b*an;
    float acc = 0.f;
    #pragma unroll
    for (int g = 0; g < 8; ++g) acc += reluf(__fmaf_rn(sp, cons[2+g], sn*cons[10+g]));
    hm[t] = 0.125f*acc;
  }
  __syncthreads();   // B12

  // ===== P13: attention pooling =====
  {
    const int n = lane;
    float a0=0.f, a1v=0.f, v0=0.f, v1=0.f;
    const int m0 = h*32;
    #pragma unroll 8
    for (int k = 0; k < 32; ++k){
      int m = m0 + k;
      float hmv = hm[m], tv = tim[m];
      float wg = Weight[(m<<7) + n], wvv = Wv[(m<<7) + n];
      a0 = __fmaf_rn(hmv, wg, a0); a1v = __fmaf_rn(tv, wg, a1v);
      v0 = __fmaf_rn(hmv, wvv, v0); v1 = __fmaf_rn(tv, wvv, v1);
    }
    pool4[h][n] = make_float4(a0, a1v, v0, v1);
  }
  __syncthreads();   // B13

  // ===== P14: A/V combine + att =====
  float att0 = 0.f, att1 = 0.f, rsv = 0.f;
  if (t < 128){
    float A0=0.f, A1=0.f, V0=0.f, V1=0.f;
    #pragma unroll
    for (int g = 0; g < 4; ++g){ float4 v = pool4[g][t]; A0+=v.x; A1+=v.y; V0+=v.z; V1+=v.w; }
    red4[0][t] = make_float2(V0, V1);
    float mx = fmaxf(A0, A1);
    att0 = fexp(A0 - mx); att1 = fexp(A1 - mx);
    rsv = frcp(att0 + att1);
  }
  __syncthreads();   // B14

  // ===== P15: hq + ips copy =====
  if (t < 128){
    float r0, r1;
    if (t < 64){ r0 = red4[0][2*t].x;     r1 = red4[0][2*t+1].x; }
    else       { r0 = red4[0][2*t-128].y; r1 = red4[0][2*t-127].y; }
    hq[t] = (reluf(r0)*att0 + reluf(r1)*att1)*rsv;
  }
  if (t >= 192 && t < 256) hq[128 + (t - 192)] = ips[t - 192];
  __syncthreads();   // B15

  // ===== P16: kv =====
  const float wq = mha_in_w[0], wk = mha_in_w[1], wvv_ = mha_in_w[2];
  const float bq = mha_in_b[0], bk = mha_in_b[1], bv = mha_in_b[2];
  const float wo = mha_out_w[0], bo = mha_out_b[0];
  if (t < 192){
    float hv_ = hq[t];
    kv[t] = make_float2(__fmaf_rn(hv_, wk, bk), __fmaf_rn(hv_, wvv_, bv));
  }
  __syncthreads();   // B16

  // ===== P17: MHA partials + redundant kmax/kmin (merged; same op order) =====
  if (t < 384){
    float k0 = kv[ln].x, k1 = kv[ln+64].x, k2 = kv[ln+128].x;
    float mx = fmaxf(fmaxf(k0, k1), k2);
    float mn = fminf(fminf(k0, k1), k2);
    #pragma unroll
    for (int off = 32; off; off >>= 1){
      mx = fmaxf(mx, __shfl_xor(mx, off));
      mn = fminf(mn, __shfl_xor(mn, off));
    }
    const int half = (t >= 192), tt = t - half*192;
    float qi = __fmaf_rn(hq[tt], wq, bq);
    float mxx = (qi >= 0.f) ? qi*mx : qi*mn;
    const float qi2 = qi*L2E, mx2 = mxx*L2E;
    float den = 0.f, num = 0.f;
    const int j0 = half*96;
    #pragma unroll 8
    for (int jj = 0; jj < 96; ++jj){
      float2 K = kv[j0 + jj];
      float e = __builtin_amdgcn_exp2f(__fmaf_rn(qi2, K.x, -mx2));
      den += e; num = __fmaf_rn(e, K.y, num);
    }
    pden[half][tt] = den; pnum[half][tt] = num;
  }
  __syncthreads();   // B17

  // ===== P18: h2s =====
  if (t < 192){
    float den = pden[0][t] + pden[1][t];
    float num = pnum[0][t] + pnum[1][t];
    h2s[t] = __fmaf_rn(num*frcp(den), wo, bo) + hq[t];
  }
  __syncthreads();   // B18

  // ===== P19: fl1 partials =====
  {
    const int n = t & 127, qtr = t >> 7;
    float acc = 0.f;
    const int i0 = qtr*48;
    #pragma unroll 8
    for (int k = 0; k < 48; ++k){
      int i = i0 + k;
      acc = __fmaf_rn(h2s[i], fl1_w[i*128 + n], acc);
    }
    red1[qtr][n] = acc;
  }
  __syncthreads();   // B19

  // ===== P20: fl1 combine =====
  if (t < 128) rho_s[t] = reluf(red1[0][t] + red1[1][t] + red1[2][t] + red1[3][t] + fl1_b[t]);
  __syncthreads();   // B20

  // ===== P21: fl2 partials =====
  if (t < 128){
    const int n = t & 31, seg = t >> 5;
    float p = 0.f;
    #pragma unroll 8
    for (int k = 0; k < 32; ++k){
      int i = seg*32 + k;
      p = __fmaf_rn(rho_s[i], fl2_w[i*32 + n], p);
    }
    red1[seg][n] = p;
  }
  __syncthreads();   // B21

  // ===== P22: fl2 combine + tanh + fl3 in wave 0 (merged; same op order) =====
  if (t < 64){
    float p = 0.f;
    if (t < 32){
      float s = red1[0][t] + red1[1][t] + red1[2][t] + red1[3][t] + fl2_b[t];
      p = tanh_n(s)*fl3_w[t];
    }
    #pragma unroll
    for (int off = 32; off; off >>= 1) p += __shfl_xor(p, off);
    if (t == 0) out[b] = reluf(p + fl3_b[0]);
  }
}

extern "C" void kernel_launch(void* const* d_in, const int* in_sizes, int n_in,
                              void* d_out, int out_size, void* d_ws, size_t ws_size,
                              hipStream_t stream) {
  const int*   adj    = (const int*)  d_in[0];
  const float* feat   = (const float*)d_in[1];
  const float* timei  = (const float*)d_in[2];
  const float* ipop   = (const float*)d_in[3];
  const float* W1     = (const float*)d_in[4];
  const float* a1     = (const float*)d_in[5];
  const float* W2     = (const float*)d_in[6];
  const float* a2     = (const float*)d_in[7];
  const float* Weight = (const float*)d_in[8];
  const float* Wv     = (const float*)d_in[9];
  const float* wih0   = (const float*)d_in[10];
  const float* whh0   = (const float*)d_in[11];
  const float* bih0   = (const float*)d_in[12];
  const float* bhh0   = (const float*)d_in[13];
  const float* wih1   = (const float*)d_in[14];
  const float* whh1   = (const float*)d_in[15];
  const float* bih1   = (const float*)d_in[16];
  const float* bhh1   = (const float*)d_in[17];
  const float* mha_in_w  = (const float*)d_in[18];
  const float* mha_in_b  = (const float*)d_in[19];
  const float* mha_out_w = (const float*)d_in[20];
  const float* mha_out_b = (const float*)d_in[21];
  const float* fl1_w = (const float*)d_in[22];
  const float* fl1_b = (const float*)d_in[23];
  const float* fl2_w = (const float*)d_in[24];
  const float* fl2_b = (const float*)d_in[25];
  const float* fl3_w = (const float*)d_in[26];
  const float* fl3_b = (const float*)d_in[27];

  fused_kernel<<<512, 512, 0, stream>>>(adj, feat, timei, Weight, Wv,
                                        W1, a1, W2, a2, ipop,
                                        wih0, whh0, bih0, bhh0,
                                        wih1, whh1, bih1, bhh1,
                                        mha_in_w, mha_in_b, mha_out_w, mha_out_b,
                                        fl1_w, fl1_b, fl2_w, fl2_b, fl3_w, fl3_b,
                                        (float*)d_out);
}

// Round 16
// 61.426 us; speedup vs baseline: 1.0586x; 1.0004x over previous
//
#include <hip/hip_runtime.h>
#include <math.h>

typedef unsigned int uint;
typedef unsigned long long ull;

#define L2E 1.44269504f

__device__ __forceinline__ float reluf(float z){ return fmaxf(z, 0.f); }
__device__ __forceinline__ float fexp(float z){ return __builtin_amdgcn_exp2f(z*L2E); }
__device__ __forceinline__ float frcp(float z){ return __builtin_amdgcn_rcpf(z); }
__device__ __forceinline__ float tanh_n(float z){
  return __fmaf_rn(2.f, __builtin_amdgcn_rcpf(1.f + __builtin_amdgcn_exp2f(-2.f*L2E*z)), -1.f);
}

// ===== ONE kernel, 512 blocks x 512 threads; GAT softmax via max-identity (branch-free) =====
// Round-11 champion restored verbatim (42.8 us). r12-r15 perturbations (min-waves bound,
// 1024 threads, barrier merges) all regressed per counters - this is the measured optimum.
__global__ __launch_bounds__(512) void fused_kernel(
    const int* __restrict__ adj, const float* __restrict__ feat,
    const float* __restrict__ timei,
    const float* __restrict__ Weight, const float* __restrict__ Wv,
    const float* __restrict__ W1, const float* __restrict__ a1,
    const float* __restrict__ W2, const float* __restrict__ a2,
    const float* __restrict__ ipop,
    const float* __restrict__ wih0, const float* __restrict__ whh0,
    const float* __restrict__ bih0, const float* __restrict__ bhh0,
    const float* __restrict__ wih1, const float* __restrict__ whh1,
    const float* __restrict__ bih1, const float* __restrict__ bhh1,
    const float* __restrict__ mha_in_w, const float* __restrict__ mha_in_b,
    const float* __restrict__ mha_out_w, const float* __restrict__ mha_out_b,
    const float* __restrict__ fl1_w, const float* __restrict__ fl1_b,
    const float* __restrict__ fl2_w, const float* __restrict__ fl2_b,
    const float* __restrict__ fl3_w, const float* __restrict__ fl3_b,
    float* __restrict__ out)
{
  const int b = blockIdx.x, t = threadIdx.x;
  const int lane = t & 127, h = t >> 7;        // h in {0,1,2,3}
  const int wv = t >> 6, ln = t & 63;

  __shared__ ull   rowW[256];
  __shared__ float xs[128], tim[128], hm[128], eAs[128], rho_s[128];
  __shared__ float2 f2a[128];                  // {E1_i, Eh_i}
  __shared__ float  red1[4][128];
  __shared__ float2 red4[4][128];
  __shared__ float4 q4[128];
  __shared__ float4 pool4[4][128];
  __shared__ float2 kv[192];
  __shared__ float  hq[192], h2s[192];
  __shared__ float  pden[2][192], pnum[2][192];
  __shared__ float  sred[8];
  __shared__ float  cpart[8][2];
  __shared__ float  pqpart[8][16];
  __shared__ float  cons[24];
  __shared__ float  ips[64];

  // ================= region A (pre-B1) =================
  if (t < 128){ xs[t] = feat[b*128 + t]; tim[t] = timei[b*128 + t]; }

  float a2reg[16];
  if (t == 0){
    #pragma unroll
    for (int g = 0; g < 16; ++g) a2reg[g] = a2[g];
  }

  // LSTM prologue (thread 511 only)
  float h1v=0.f, c1s=0.f, h2v=0.f, c2s=0.f;
  float wi0s[4], wh0s[4], bb0s[4], wi1s[4], wh1s[4], bb1s[4];
  const float4* xsrc4 = (const float4*)(ipop + b*64);
  float4 xcur0, xcur1;
  if (t == 511){
    #pragma unroll
    for (int k = 0; k < 4; ++k){
      const float s = (k == 2) ? -2.f*L2E : -L2E;
      wi0s[k]=wih0[k]*s; wh0s[k]=whh0[k]*s; bb0s[k]=(bih0[k]+bhh0[k])*s;
      wi1s[k]=wih1[k]*s; wh1s[k]=whh1[k]*s; bb1s[k]=(bih1[k]+bhh1[k])*s;
    }
    xcur0 = xsrc4[0]; xcur1 = xsrc4[1];
  }
  auto lstm8 = [&](int c){
    if (t != 511) return;
    const float4 xa = xcur0, xb = xcur1;
    if (c < 7){ xcur0 = xsrc4[2*c+2]; xcur1 = xsrc4[2*c+3]; }
    float o[8];
    #pragma unroll
    for (int si = 0; si < 8; ++si){
      const float x = (si==0)?xa.x:(si==1)?xa.y:(si==2)?xa.z:(si==3)?xa.w:
                      (si==4)?xb.x:(si==5)?xb.y:(si==6)?xb.z:xb.w;
      float gi = frcp(1.f + __builtin_amdgcn_exp2f(__fmaf_rn(x, wi0s[0], __fmaf_rn(h1v, wh0s[0], bb0s[0]))));
      float gf = frcp(1.f + __builtin_amdgcn_exp2f(__fmaf_rn(x, wi0s[1], __fmaf_rn(h1v, wh0s[1], bb0s[1]))));
      float gg = __fmaf_rn(2.f, frcp(1.f + __builtin_amdgcn_exp2f(__fmaf_rn(x, wi0s[2], __fmaf_rn(h1v, wh0s[2], bb0s[2])))), -1.f);
      float go = frcp(1.f + __builtin_amdgcn_exp2f(__fmaf_rn(x, wi0s[3], __fmaf_rn(h1v, wh0s[3], bb0s[3]))));
      c1s = gf*c1s + gi*gg;  h1v = go*tanh_n(c1s);
      float hi = frcp(1.f + __builtin_amdgcn_exp2f(__fmaf_rn(h1v, wi1s[0], __fmaf_rn(h2v, wh1s[0], bb1s[0]))));
      float hf = frcp(1.f + __builtin_amdgcn_exp2f(__fmaf_rn(h1v, wi1s[1], __fmaf_rn(h2v, wh1s[1], bb1s[1]))));
      float hg = __fmaf_rn(2.f, frcp(1.f + __builtin_amdgcn_exp2f(__fmaf_rn(h1v, wi1s[2], __fmaf_rn(h2v, wh1s[2], bb1s[2])))), -1.f);
      float ho = frcp(1.f + __builtin_amdgcn_exp2f(__fmaf_rn(h1v, wi1s[3], __fmaf_rn(h2v, wh1s[3], bb1s[3])))) ;
      c2s = hf*c2s + hi*hg;  h2v = ho*tanh_n(c2s);
      o[si] = h2v;
    }
    #pragma unroll
    for (int si = 0; si < 8; ++si) ips[8*c + si] = o[si];
  };

  // ballot pack
  {
    const int* abase = adj + (((long)b) << 14) + wv*2048 + ln;
    ull myword = 0;
    #pragma unroll
    for (int blk = 0; blk < 4; ++blk){
      int v[8];
      #pragma unroll
      for (int q = 0; q < 8; ++q) v[q] = abase[(blk*8 + q)*64];
      #pragma unroll
      for (int q = 0; q < 8; ++q){
        ull m = __ballot(v[q] > 0);
        myword = (ln == blk*8 + q) ? m : myword;
      }
    }
    if (ln < 32) rowW[wv*32 + ln] = myword;
  }

  // consts partials
  {
    float w0 = W1[t];
    float s1 = w0*a1[t];
    float s2 = w0*a1[512+t];
    #pragma unroll
    for (int off = 32; off; off >>= 1){ s1 += __shfl_xor(s1, off); s2 += __shfl_xor(s2, off); }
    if (ln == 0){ cpart[wv][0] = s1; cpart[wv][1] = s2; }
  }
  {
    const float w = W1[t];
    const float wp = fmaxf(w, 0.f), wn = fminf(w, 0.f);
    const float4 A = *(const float4*)(W2 + t*8);
    const float4 Bv = *(const float4*)(W2 + t*8 + 4);
    float accP[8], accQ[8];
    accP[0]=wp*A.x;  accQ[0]=wn*A.x;   accP[1]=wp*A.y;  accQ[1]=wn*A.y;
    accP[2]=wp*A.z;  accQ[2]=wn*A.z;   accP[3]=wp*A.w;  accQ[3]=wn*A.w;
    accP[4]=wp*Bv.x; accQ[4]=wn*Bv.x;  accP[5]=wp*Bv.y; accQ[5]=wn*Bv.y;
    accP[6]=wp*Bv.z; accQ[6]=wn*Bv.z;  accP[7]=wp*Bv.w; accQ[7]=wn*Bv.w;
    #pragma unroll
    for (int g = 0; g < 8; ++g){
      float p = accP[g], q = accQ[g];
      #pragma unroll
      for (int off = 32; off; off >>= 1){ p += __shfl_xor(p, off); q += __shfl_xor(q, off); }
      if (ln == 0){ pqpart[wv][g] = p; pqpart[wv][8+g] = q; }
    }
  }
  __syncthreads();   // B1

  // ================= region B =================
  const uint rowm = (uint)(rowW[lane*2 + (h>>1)] >> ((h&1)*32));
  uint colm = 0;
  {
    const int wsel = lane >> 6, bsel = lane & 63;
    #pragma unroll
    for (int k = 0; k < 32; ++k)
      colm |= (uint)((rowW[(32*h + k)*2 + wsel] >> bsel) & 1ull) << k;
  }
  if (t < 64){
    float mx = fmaxf(xs[t], xs[t+64]);
    float mn = fminf(xs[t], xs[t+64]);
    #pragma unroll
    for (int off = 32; off; off >>= 1){
      mx = fmaxf(mx, __shfl_xor(mx, off));
      mn = fminf(mn, __shfl_xor(mn, off));
    }
    if (t == 0){ sred[0] = mx; sred[1] = mn; }
  }
  if (t == 0){
    float c1v = 0.f, c2v = 0.f;
    #pragma unroll
    for (int wvi = 0; wvi < 8; ++wvi){ c1v += cpart[wvi][0]; c2v += cpart[wvi][1]; }
    cons[0] = c1v; cons[1] = c2v;
    float pAx=0.f, qAx=0.f, pBx=0.f, qBx=0.f;
    #pragma unroll
    for (int g = 0; g < 8; ++g){
      float P = 0.f, Q = 0.f;
      #pragma unroll
      for (int wvi = 0; wvi < 8; ++wvi){ P += pqpart[wvi][g]; Q += pqpart[wvi][8+g]; }
      cons[2+g] = P; cons[10+g] = Q;
      pAx = __fmaf_rn(P, a2reg[g],   pAx);  qAx = __fmaf_rn(Q, a2reg[g],   qAx);
      pBx = __fmaf_rn(P, a2reg[8+g], pBx);  qBx = __fmaf_rn(Q, a2reg[8+g], qBx);
    }
    cons[18]=pAx; cons[19]=qAx; cons[20]=pBx; cons[21]=qBx;
  }
  lstm8(0);
  __syncthreads();   // B2

  // ====== GAT1 factors: att_ij = max(E1_i, rho_j*Eh_i)/s_j (A_j cancels) ======
  float myE1=0.f, myRho=0.f, myx=0.f;
  {
    const float c1 = cons[0], c2 = cons[1];
    const float rmax = (c1 >= 0.f) ? c1*sred[0] : c1*sred[1];
    if (t < 128){
      myx = xs[t];
      float r  = c1*myx;
      float cj = c2*myx;
      float d  = r - rmax;
      myE1 = fexp(d);
      float Eh = fexp(0.5f*d);
      myRho = fexp(-0.5f*fmaxf(rmax + cj, -170.f));
      f2a[t] = make_float2(myE1, Eh);
      rho_s[t] = myRho;
    }
  }
  lstm8(1);
  __syncthreads();   // B3

  // ---- GAT1 col pass: s_j = sum_i m*max(E1_i, rho_j*Eh_i) ----
  {
    const float rho = rho_s[lane];
    float s = 0.f;
    #pragma unroll 8
    for (int k = 0; k < 32; ++k){
      float2 E = f2a[32*h + k];
      float v = fmaxf(E.x, rho*E.y);
      s += ((colm >> k) & 1u) ? v : 0.f;
    }
    red1[h][lane] = s;
  }
  lstm8(2);
  __syncthreads();   // B4

  if (t < 128){
    float s = red1[0][t] + red1[1][t] + red1[2][t] + red1[3][t];
    float sinv = frcp(s);
    float ax = fabsf(myx)*sinv;
    q4[t] = make_float4(ax, myRho*ax, (myx >= 0.f) ? 1.f : -1.f, 0.f);
  }
  lstm8(3);
  __syncthreads();   // B5

  // ---- GAT1 row pass: u_i = E1_i * sum_j m*sgn_j*max(G1_j, om_i*G2_j) ----
  {
    const float om = frcp(f2a[lane].y);
    float acc = 0.f;
    #pragma unroll 8
    for (int k = 0; k < 32; ++k){
      float4 G = q4[32*h + k];
      float v = fmaxf(G.x, om*G.y);
      float sg = ((rowm >> k) & 1u) ? G.z : 0.f;
      acc = __fmaf_rn(v, sg, acc);
    }
    red1[h][lane] = acc;
  }
  lstm8(4);
  __syncthreads();   // B6

  float u = 0.f, eBv = 0.f, eAv = 0.f;
  if (t < 128){
    u = myE1*(red1[0][t] + red1[1][t] + red1[2][t] + red1[3][t]);
    eAv = (u >= 0.f ? cons[18] : cons[19])*u;
    eBv = (u >= 0.f ? cons[20] : cons[21])*u;
    eAs[t] = eAv;
  }
  lstm8(5);
  __syncthreads();   // B7

  if (t < 64){
    float mx = fmaxf(eAs[t], eAs[t+64]);
    #pragma unroll
    for (int off = 32; off; off >>= 1) mx = fmaxf(mx, __shfl_xor(mx, off));
    if (t == 0) sred[2] = mx;
  }
  lstm8(6);
  __syncthreads();   // B8

  // ====== GAT2 factors ======
  float myE1b=0.f;
  {
    const float eAmax = sred[2];
    if (t < 128){
      float d2 = eAv - eAmax;
      myE1b = fexp(d2);
      float Ehb = fexp(0.5f*d2);
      float rho2 = fexp(-0.5f*fmaxf(eAmax + eBv, -170.f));
      f2a[t] = make_float2(myE1b, Ehb);
      rho_s[t] = rho2;
    }
  }
  lstm8(7);
  __syncthreads();   // B9

  // ---- GAT2 col pass ----
  {
    const float rho = rho_s[lane];
    float s = 0.f;
    #pragma unroll 8
    for (int k = 0; k < 32; ++k){
      float2 E = f2a[32*h + k];
      float v = fmaxf(E.x, rho*E.y);
      s += ((colm >> k) & 1u) ? v : 0.f;
    }
    red1[h][lane] = s;
  }
  __syncthreads();   // B10

  if (t < 128){
    float s = red1[0][t] + red1[1][t] + red1[2][t] + red1[3][t];
    float sinv = frcp(s);
    float rho2 = rho_s[t];
    float up = fmaxf(u, 0.f)*sinv, un = -fminf(u, 0.f)*sinv;
    q4[t] = make_float4(up, rho2*up, un, rho2*un);
  }
  __syncthreads();   // B11

  // ---- GAT2 row pass: sp = E1b*accp, sn = -E1b*accn ----
  {
    const float om = frcp(f2a[lane].y);
    float accp = 0.f, accn = 0.f;
    #pragma unroll 8
    for (int k = 0; k < 32; ++k){
      float4 G = q4[32*h + k];
      bool m = ((rowm >> k) & 1u);
      float v1 = fmaxf(G.x, om*G.y);
      float v2 = fmaxf(G.z, om*G.w);
      accp += m ? v1 : 0.f;
      accn += m ? v2 : 0.f;
    }
    red4[h][lane] = make_float2(accp, accn);
  }
  __syncthreads();   // B12

  if (t < 128){
    float ap=0.f, an=0.f;
    #pragma unroll
    for (int g = 0; g < 4; ++g){ float2 v = red4[g][t]; ap += v.x; an += v.y; }
    float sp = myE1b*ap, sn = -myE1b*an;
    float acc = 0.f;
    #pragma unroll
    for (int g = 0; g < 8; ++g) acc += reluf(__fmaf_rn(sp, cons[2+g], sn*cons[10+g]));
    hm[t] = 0.125f*acc;
  }
  __syncthreads();   // B13

  // ---- attention pooling ----
  {
    const int n = lane;
    float a0=0.f, a1v=0.f, v0=0.f, v1=0.f;
    const int m0 = h*32;
    #pragma unroll 8
    for (int k = 0; k < 32; ++k){
      int m = m0 + k;
      float hmv = hm[m], tv = tim[m];
      float wg = Weight[(m<<7) + n], wvv = Wv[(m<<7) + n];
      a0 = __fmaf_rn(hmv, wg, a0); a1v = __fmaf_rn(tv, wg, a1v);
      v0 = __fmaf_rn(hmv, wvv, v0); v1 = __fmaf_rn(tv, wvv, v1);
    }
    pool4[h][n] = make_float4(a0, a1v, v0, v1);
  }
  __syncthreads();   // B14

  float att0 = 0.f, att1 = 0.f, rsv = 0.f;
  if (t < 128){
    float A0=0.f, A1=0.f, V0=0.f, V1=0.f;
    #pragma unroll
    for (int g = 0; g < 4; ++g){ float4 v = pool4[g][t]; A0+=v.x; A1+=v.y; V0+=v.z; V1+=v.w; }
    red4[0][t] = make_float2(V0, V1);
    float mx = fmaxf(A0, A1);
    att0 = fexp(A0 - mx); att1 = fexp(A1 - mx);
    rsv = frcp(att0 + att1);
  }
  __syncthreads();   // B15

  if (t < 128){
    float r0, r1;
    if (t < 64){ r0 = red4[0][2*t].x;     r1 = red4[0][2*t+1].x; }
    else       { r0 = red4[0][2*t-128].y; r1 = red4[0][2*t-127].y; }
    hq[t] = (reluf(r0)*att0 + reluf(r1)*att1)*rsv;
  }
  if (t >= 192 && t < 256) hq[128 + (t - 192)] = ips[t - 192];
  __syncthreads();   // B16

  // ---- MHA ----
  const float wq = mha_in_w[0], wk = mha_in_w[1], wvv_ = mha_in_w[2];
  const float bq = mha_in_b[0], bk = mha_in_b[1], bv = mha_in_b[2];
  const float wo = mha_out_w[0], bo = mha_out_b[0];
  if (t < 192){
    float hv_ = hq[t];
    kv[t] = make_float2(__fmaf_rn(hv_, wk, bk), __fmaf_rn(hv_, wvv_, bv));
  }
  __syncthreads();   // B17

  if (t < 64){
    float k0 = kv[t].x, k1 = kv[t+64].x, k2 = kv[t+128].x;
    float mx = fmaxf(fmaxf(k0, k1), k2);
    float mn = fminf(fminf(k0, k1), k2);
    #pragma unroll
    for (int off = 32; off; off >>= 1){
      mx = fmaxf(mx, __shfl_xor(mx, off));
      mn = fminf(mn, __shfl_xor(mn, off));
    }
    if (t == 0){ sred[3] = mx; sred[4] = mn; }
  }
  __syncthreads();   // B18

  if (t < 384){
    const int half = (t >= 192), tt = t - half*192;
    float qi = __fmaf_rn(hq[tt], wq, bq);
    float mx = (qi >= 0.f) ? qi*sred[3] : qi*sred[4];
    const float qi2 = qi*L2E, mx2 = mx*L2E;
    float den = 0.f, num = 0.f;
    const int j0 = half*96;
    #pragma unroll 8
    for (int jj = 0; jj < 96; ++jj){
      float2 K = kv[j0 + jj];
      float e = __builtin_amdgcn_exp2f(__fmaf_rn(qi2, K.x, -mx2));
      den += e; num = __fmaf_rn(e, K.y, num);
    }
    pden[half][tt] = den; pnum[half][tt] = num;
  }
  __syncthreads();   // B19

  if (t < 192){
    float den = pden[0][t] + pden[1][t];
    float num = pnum[0][t] + pnum[1][t];
    h2s[t] = __fmaf_rn(num*frcp(den), wo, bo) + hq[t];
  }
  __syncthreads();   // B20

  // ---- fl1: 192->128 (4-way split) ----
  {
    const int n = t & 127, qtr = t >> 7;
    float acc = 0.f;
    const int i0 = qtr*48;
    #pragma unroll 8
    for (int k = 0; k < 48; ++k){
      int i = i0 + k;
      acc = __fmaf_rn(h2s[i], fl1_w[i*128 + n], acc);
    }
    red4[qtr][n].x = acc;
  }
  __syncthreads();   // B21

  if (t < 128) rho_s[t] = reluf(red4[0][t].x + red4[1][t].x + red4[2][t].x + red4[3][t].x + fl1_b[t]);
  __syncthreads();   // B22

  // ---- fl2: 128->32 (4-way split) ----
  if (t < 128){
    const int n = t & 31, seg = t >> 5;
    float p = 0.f;
    #pragma unroll 8
    for (int k = 0; k < 32; ++k){
      int i = seg*32 + k;
      p = __fmaf_rn(rho_s[i], fl2_w[i*32 + n], p);
    }
    eAs[t] = p;
  }
  __syncthreads();   // B23

  if (t < 32) hm[t] = tanh_n(eAs[t] + eAs[t+32] + eAs[t+64] + eAs[t+96] + fl2_b[t]);
  __syncthreads();   // B24

  // ---- fl3: 32->1 ----
  if (t < 64){
    float p = (t < 32) ? hm[t]*fl3_w[t] : 0.f;
    #pragma unroll
    for (int off = 32; off; off >>= 1) p += __shfl_xor(p, off);
    if (t == 0) out[b] = reluf(p + fl3_b[0]);
  }
}

extern "C" void kernel_launch(void* const* d_in, const int* in_sizes, int n_in,
                              void* d_out, int out_size, void* d_ws, size_t ws_size,
                              hipStream_t stream) {
  const int*   adj    = (const int*)  d_in[0];
  const float* feat   = (const float*)d_in[1];
  const float* timei  = (const float*)d_in[2];
  const float* ipop   = (const float*)d_in[3];
  const float* W1     = (const float*)d_in[4];
  const float* a1     = (const float*)d_in[5];
  const float* W2     = (const float*)d_in[6];
  const float* a2     = (const float*)d_in[7];
  const float* Weight = (const float*)d_in[8];
  const float* Wv     = (const float*)d_in[9];
  const float* wih0   = (const float*)d_in[10];
  const float* whh0   = (const float*)d_in[11];
  const float* bih0   = (const float*)d_in[12];
  const float* bhh0   = (const float*)d_in[13];
  const float* wih1   = (const float*)d_in[14];
  const float* whh1   = (const float*)d_in[15];
  const float* bih1   = (const float*)d_in[16];
  const float* bhh1   = (const float*)d_in[17];
  const float* mha_in_w  = (const float*)d_in[18];
  const float* mha_in_b  = (const float*)d_in[19];
  const float* mha_out_w = (const float*)d_in[20];
  const float* mha_out_b = (const float*)d_in[21];
  const float* fl1_w = (const float*)d_in[22];
  const float* fl1_b = (const float*)d_in[23];
  const float* fl2_w = (const float*)d_in[24];
  const float* fl2_b = (const float*)d_in[25];
  const float* fl3_w = (const float*)d_in[26];
  const float* fl3_b = (const float*)d_in[27];

  fused_kernel<<<512, 512, 0, stream>>>(adj, feat, timei, Weight, Wv,
                                        W1, a1, W2, a2, ipop,
                                        wih0, whh0, bih0, bhh0,
                                        wih1, whh1, bih1, bhh1,
                                        mha_in_w, mha_in_b, mha_out_w, mha_out_b,
                                        fl1_w, fl1_b, fl2_w, fl2_b, fl3_w, fl3_b,
                                        (float*)d_out);
}

// Round 17
// 42.846 us; speedup vs baseline: 1.5176x; 1.4337x over previous
//
#include <hip/hip_runtime.h>
#include <math.h>

typedef unsigned int uint;
typedef unsigned long long ull;

#define L2E 1.44269504f

__device__ __forceinline__ float lrelu(float z){ return fmaxf(z, 0.5f*z); }
__device__ __forceinline__ float reluf(float z){ return fmaxf(z, 0.f); }
__device__ __forceinline__ float fexp(float z){ return __builtin_amdgcn_exp2f(z*L2E); }
__device__ __forceinline__ float frcp(float z){ return __builtin_amdgcn_rcpf(z); }
__device__ __forceinline__ float tanh_n(float z){
  return __fmaf_rn(2.f, __builtin_amdgcn_rcpf(1.f + __builtin_amdgcn_exp2f(-2.f*L2E*z)), -1.f);
}

// ===== ONE kernel, 512 blocks x 512 threads; GAT softmax via max-identity (branch-free) =====
// BYTE-EXACT round-11 champion (measured 42.8 us, VGPR 56). The r15/r16 "restores" carried
// stowaway unroll pragmas (colm full-unroll, pooling unroll-8) that blew VGPR to 104.
__global__ __launch_bounds__(512) void fused_kernel(
    const int* __restrict__ adj, const float* __restrict__ feat,
    const float* __restrict__ timei,
    const float* __restrict__ Weight, const float* __restrict__ Wv,
    const float* __restrict__ W1, const float* __restrict__ a1,
    const float* __restrict__ W2, const float* __restrict__ a2,
    const float* __restrict__ ipop,
    const float* __restrict__ wih0, const float* __restrict__ whh0,
    const float* __restrict__ bih0, const float* __restrict__ bhh0,
    const float* __restrict__ wih1, const float* __restrict__ whh1,
    const float* __restrict__ bih1, const float* __restrict__ bhh1,
    const float* __restrict__ mha_in_w, const float* __restrict__ mha_in_b,
    const float* __restrict__ mha_out_w, const float* __restrict__ mha_out_b,
    const float* __restrict__ fl1_w, const float* __restrict__ fl1_b,
    const float* __restrict__ fl2_w, const float* __restrict__ fl2_b,
    const float* __restrict__ fl3_w, const float* __restrict__ fl3_b,
    float* __restrict__ out)
{
  const int b = blockIdx.x, t = threadIdx.x;
  const int lane = t & 127, h = t >> 7;        // h in {0,1,2,3}
  const int wv = t >> 6, ln = t & 63;

  __shared__ ull   rowW[256];
  __shared__ float xs[128], tim[128], hm[128], eAs[128], rho_s[128];
  __shared__ float2 f2a[128];                  // {E1_i, Eh_i}
  __shared__ float  red1[4][128];              // scalar pass partials
  __shared__ float2 red4[4][128];              // GAT2-row / pooling-V / fl1 partials
  __shared__ float4 q4[128];                   // {G1,G2,thr,-} then {Gp1,Gp2,Gn1,Gn2}
  __shared__ float4 pool4[4][128];             // row2 partials / pooling partials
  __shared__ float2 kv[192];
  __shared__ float  hq[192], h2s[192];
  __shared__ float  pden[2][192], pnum[2][192];
  __shared__ float  sred[8];
  __shared__ float  cpart[8][2];
  __shared__ float  pqpart[8][16];
  __shared__ float  cons[24];
  __shared__ float  ips[64];

  // ================= region A (pre-B1) =================
  if (t < 128){ xs[t] = feat[b*128 + t]; tim[t] = timei[b*128 + t]; }

  float a2reg[16];
  if (t == 0){
    #pragma unroll
    for (int g = 0; g < 16; ++g) a2reg[g] = a2[g];
  }

  // LSTM prologue (thread 511 only)
  float h1v=0.f, c1s=0.f, h2v=0.f, c2s=0.f;
  float wi0s[4], wh0s[4], bb0s[4], wi1s[4], wh1s[4], bb1s[4];
  const float4* xsrc4 = (const float4*)(ipop + b*64);
  float4 xcur0, xcur1;
  if (t == 511){
    #pragma unroll
    for (int k = 0; k < 4; ++k){
      const float s = (k == 2) ? -2.f*L2E : -L2E;
      wi0s[k]=wih0[k]*s; wh0s[k]=whh0[k]*s; bb0s[k]=(bih0[k]+bhh0[k])*s;
      wi1s[k]=wih1[k]*s; wh1s[k]=whh1[k]*s; bb1s[k]=(bih1[k]+bhh1[k])*s;
    }
    xcur0 = xsrc4[0]; xcur1 = xsrc4[1];
  }
  auto lstm8 = [&](int c){
    if (t != 511) return;
    const float4 xa = xcur0, xb = xcur1;
    if (c < 7){ xcur0 = xsrc4[2*c+2]; xcur1 = xsrc4[2*c+3]; }
    float o[8];
    #pragma unroll
    for (int si = 0; si < 8; ++si){
      const float x = (si==0)?xa.x:(si==1)?xa.y:(si==2)?xa.z:(si==3)?xa.w:
                      (si==4)?xb.x:(si==5)?xb.y:(si==6)?xb.z:xb.w;
      float gi = frcp(1.f + __builtin_amdgcn_exp2f(__fmaf_rn(x, wi0s[0], __fmaf_rn(h1v, wh0s[0], bb0s[0]))));
      float gf = frcp(1.f + __builtin_amdgcn_exp2f(__fmaf_rn(x, wi0s[1], __fmaf_rn(h1v, wh0s[1], bb0s[1]))));
      float gg = __fmaf_rn(2.f, frcp(1.f + __builtin_amdgcn_exp2f(__fmaf_rn(x, wi0s[2], __fmaf_rn(h1v, wh0s[2], bb0s[2])))), -1.f);
      float go = frcp(1.f + __builtin_amdgcn_exp2f(__fmaf_rn(x, wi0s[3], __fmaf_rn(h1v, wh0s[3], bb0s[3]))));
      c1s = gf*c1s + gi*gg;  h1v = go*tanh_n(c1s);
      float hi = frcp(1.f + __builtin_amdgcn_exp2f(__fmaf_rn(h1v, wi1s[0], __fmaf_rn(h2v, wh1s[0], bb1s[0]))));
      float hf = frcp(1.f + __builtin_amdgcn_exp2f(__fmaf_rn(h1v, wi1s[1], __fmaf_rn(h2v, wh1s[1], bb1s[1]))));
      float hg = __fmaf_rn(2.f, frcp(1.f + __builtin_amdgcn_exp2f(__fmaf_rn(h1v, wi1s[2], __fmaf_rn(h2v, wh1s[2], bb1s[2])))), -1.f);
      float ho = frcp(1.f + __builtin_amdgcn_exp2f(__fmaf_rn(h1v, wi1s[3], __fmaf_rn(h2v, wh1s[3], bb1s[3])))) ;
      c2s = hf*c2s + hi*hg;  h2v = ho*tanh_n(c2s);
      o[si] = h2v;
    }
    #pragma unroll
    for (int si = 0; si < 8; ++si) ips[8*c + si] = o[si];
  };

  // ballot pack
  {
    const int* abase = adj + (((long)b) << 14) + wv*2048 + ln;
    ull myword = 0;
    #pragma unroll
    for (int blk = 0; blk < 4; ++blk){
      int v[8];
      #pragma unroll
      for (int q = 0; q < 8; ++q) v[q] = abase[(blk*8 + q)*64];
      #pragma unroll
      for (int q = 0; q < 8; ++q){
        ull m = __ballot(v[q] > 0);
        myword = (ln == blk*8 + q) ? m : myword;
      }
    }
    if (ln < 32) rowW[wv*32 + ln] = myword;
  }

  // consts partials
  {
    float w0 = W1[t];
    float s1 = w0*a1[t];
    float s2 = w0*a1[512+t];
    #pragma unroll
    for (int off = 32; off; off >>= 1){ s1 += __shfl_xor(s1, off); s2 += __shfl_xor(s2, off); }
    if (ln == 0){ cpart[wv][0] = s1; cpart[wv][1] = s2; }
  }
  {
    const float w = W1[t];
    const float wp = fmaxf(w, 0.f), wn = fminf(w, 0.f);
    const float4 A = *(const float4*)(W2 + t*8);
    const float4 Bv = *(const float4*)(W2 + t*8 + 4);
    float accP[8], accQ[8];
    accP[0]=wp*A.x;  accQ[0]=wn*A.x;   accP[1]=wp*A.y;  accQ[1]=wn*A.y;
    accP[2]=wp*A.z;  accQ[2]=wn*A.z;   accP[3]=wp*A.w;  accQ[3]=wn*A.w;
    accP[4]=wp*Bv.x; accQ[4]=wn*Bv.x;  accP[5]=wp*Bv.y; accQ[5]=wn*Bv.y;
    accP[6]=wp*Bv.z; accQ[6]=wn*Bv.z;  accP[7]=wp*Bv.w; accQ[7]=wn*Bv.w;
    #pragma unroll
    for (int g = 0; g < 8; ++g){
      float p = accP[g], q = accQ[g];
      #pragma unroll
      for (int off = 32; off; off >>= 1){ p += __shfl_xor(p, off); q += __shfl_xor(q, off); }
      if (ln == 0){ pqpart[wv][g] = p; pqpart[wv][8+g] = q; }
    }
  }
  __syncthreads();   // B1

  // ================= region B =================
  const uint rowm = (uint)(rowW[lane*2 + (h>>1)] >> ((h&1)*32));
  uint colm = 0;
  {
    const int wsel = lane >> 6, bsel = lane & 63;
    #pragma unroll 8
    for (int k = 0; k < 32; ++k)
      colm |= (uint)((rowW[(32*h + k)*2 + wsel] >> bsel) & 1ull) << k;
  }
  if (t < 64){
    float mx = fmaxf(xs[t], xs[t+64]);
    float mn = fminf(xs[t], xs[t+64]);
    #pragma unroll
    for (int off = 32; off; off >>= 1){
      mx = fmaxf(mx, __shfl_xor(mx, off));
      mn = fminf(mn, __shfl_xor(mn, off));
    }
    if (t == 0){ sred[0] = mx; sred[1] = mn; }
  }
  if (t == 0){
    float c1v = 0.f, c2v = 0.f;
    #pragma unroll
    for (int wvi = 0; wvi < 8; ++wvi){ c1v += cpart[wvi][0]; c2v += cpart[wvi][1]; }
    cons[0] = c1v; cons[1] = c2v;
    float pAx=0.f, qAx=0.f, pBx=0.f, qBx=0.f;
    #pragma unroll
    for (int g = 0; g < 8; ++g){
      float P = 0.f, Q = 0.f;
      #pragma unroll
      for (int wvi = 0; wvi < 8; ++wvi){ P += pqpart[wvi][g]; Q += pqpart[wvi][8+g]; }
      cons[2+g] = P; cons[10+g] = Q;
      pAx = __fmaf_rn(P, a2reg[g],   pAx);  qAx = __fmaf_rn(Q, a2reg[g],   qAx);
      pBx = __fmaf_rn(P, a2reg[8+g], pBx);  qBx = __fmaf_rn(Q, a2reg[8+g], qBx);
    }
    cons[18]=pAx; cons[19]=qAx; cons[20]=pBx; cons[21]=qBx;
  }
  lstm8(0);
  __syncthreads();   // B2

  // ====== GAT1 factors: att_ij = max(E1_i, rho_j*Eh_i)/s_j (A_j cancels) ======
  float myE1=0.f, myRho=0.f, myx=0.f;
  {
    const float c1 = cons[0], c2 = cons[1];
    const float rmax = (c1 >= 0.f) ? c1*sred[0] : c1*sred[1];
    if (t < 128){
      myx = xs[t];
      float r  = c1*myx;
      float cj = c2*myx;
      float d  = r - rmax;
      myE1 = fexp(d);
      float Eh = fexp(0.5f*d);
      myRho = fexp(-0.5f*fmaxf(rmax + cj, -170.f));   // clamp: overflow guard only
      f2a[t] = make_float2(myE1, Eh);
      rho_s[t] = myRho;
    }
  }
  lstm8(1);
  __syncthreads();   // B3

  // ---- GAT1 col pass: s_j = sum_i m*max(E1_i, rho_j*Eh_i) ----
  {
    const float rho = rho_s[lane];
    float s = 0.f;
    #pragma unroll 8
    for (int k = 0; k < 32; ++k){
      float2 E = f2a[32*h + k];
      float v = fmaxf(E.x, rho*E.y);
      s += ((colm >> k) & 1u) ? v : 0.f;
    }
    red1[h][lane] = s;
  }
  lstm8(2);
  __syncthreads();   // B4

  if (t < 128){
    float s = red1[0][t] + red1[1][t] + red1[2][t] + red1[3][t];
    float sinv = frcp(s);
    float ax = fabsf(myx)*sinv;
    q4[t] = make_float4(ax, myRho*ax, (myx >= 0.f) ? 1.f : -1.f, 0.f);
  }
  lstm8(3);
  __syncthreads();   // B5

  // ---- GAT1 row pass: u_i = E1_i * sum_j m*sgn_j*max(G1_j, om_i*G2_j) ----
  {
    const float om = frcp(f2a[lane].y);     // om_i = Eh/E1 = 1/Eh
    float acc = 0.f;
    #pragma unroll 8
    for (int k = 0; k < 32; ++k){
      float4 G = q4[32*h + k];
      float v = fmaxf(G.x, om*G.y);
      float sg = ((rowm >> k) & 1u) ? G.z : 0.f;
      acc = __fmaf_rn(v, sg, acc);
    }
    red1[h][lane] = acc;
  }
  lstm8(4);
  __syncthreads();   // B6

  float u = 0.f, eBv = 0.f, eAv = 0.f;
  if (t < 128){
    u = myE1*(red1[0][t] + red1[1][t] + red1[2][t] + red1[3][t]);
    eAv = (u >= 0.f ? cons[18] : cons[19])*u;
    eBv = (u >= 0.f ? cons[20] : cons[21])*u;
    eAs[t] = eAv;
  }
  lstm8(5);
  __syncthreads();   // B7

  if (t < 64){
    float mx = fmaxf(eAs[t], eAs[t+64]);
    #pragma unroll
    for (int off = 32; off; off >>= 1) mx = fmaxf(mx, __shfl_xor(mx, off));
    if (t == 0) sred[2] = mx;
  }
  lstm8(6);
  __syncthreads();   // B8

  // ====== GAT2 factors ======
  float myE1b=0.f;
  {
    const float eAmax = sred[2];
    if (t < 128){
      float d2 = eAv - eAmax;
      myE1b = fexp(d2);
      float Ehb = fexp(0.5f*d2);
      float rho2 = fexp(-0.5f*fmaxf(eAmax + eBv, -170.f));
      f2a[t] = make_float2(myE1b, Ehb);
      rho_s[t] = rho2;
    }
  }
  lstm8(7);
  __syncthreads();   // B9

  // ---- GAT2 col pass ----
  {
    const float rho = rho_s[lane];
    float s = 0.f;
    #pragma unroll 8
    for (int k = 0; k < 32; ++k){
      float2 E = f2a[32*h + k];
      float v = fmaxf(E.x, rho*E.y);
      s += ((colm >> k) & 1u) ? v : 0.f;
    }
    red1[h][lane] = s;
  }
  __syncthreads();   // B10

  if (t < 128){
    float s = red1[0][t] + red1[1][t] + red1[2][t] + red1[3][t];
    float sinv = frcp(s);
    float rho2 = rho_s[t];
    float up = fmaxf(u, 0.f)*sinv, un = -fminf(u, 0.f)*sinv;
    q4[t] = make_float4(up, rho2*up, un, rho2*un);
  }
  __syncthreads();   // B11

  // ---- GAT2 row pass: sp = E1b*accp, sn = -E1b*accn ----
  {
    const float om = frcp(f2a[lane].y);
    float accp = 0.f, accn = 0.f;
    #pragma unroll 8
    for (int k = 0; k < 32; ++k){
      float4 G = q4[32*h + k];
      bool m = ((rowm >> k) & 1u);
      float v1 = fmaxf(G.x, om*G.y);
      float v2 = fmaxf(G.z, om*G.w);
      accp += m ? v1 : 0.f;
      accn += m ? v2 : 0.f;
    }
    red4[h][lane] = make_float2(accp, accn);
  }
  __syncthreads();   // B12

  if (t < 128){
    float ap=0.f, an=0.f;
    #pragma unroll
    for (int g = 0; g < 4; ++g){ float2 v = red4[g][t]; ap += v.x; an += v.y; }
    float sp = myE1b*ap, sn = -myE1b*an;
    float acc = 0.f;
    #pragma unroll
    for (int g = 0; g < 8; ++g) acc += reluf(__fmaf_rn(sp, cons[2+g], sn*cons[10+g]));
    hm[t] = 0.125f*acc;
  }
  __syncthreads();   // B13

  // ---- attention pooling ----
  {
    const int n = lane;
    float a0=0.f, a1v=0.f, v0=0.f, v1=0.f;
    const int m0 = h*32;
    #pragma unroll 4
    for (int k = 0; k < 32; ++k){
      int m = m0 + k;
      float hmv = hm[m], tv = tim[m];
      float wg = Weight[(m<<7) + n], wvv = Wv[(m<<7) + n];
      a0 = __fmaf_rn(hmv, wg, a0); a1v = __fmaf_rn(tv, wg, a1v);
      v0 = __fmaf_rn(hmv, wvv, v0); v1 = __fmaf_rn(tv, wvv, v1);
    }
    pool4[h][n] = make_float4(a0, a1v, v0, v1);
  }
  __syncthreads();   // B14

  float att0 = 0.f, att1 = 0.f, rsv = 0.f;
  if (t < 128){
    float A0=0.f, A1=0.f, V0=0.f, V1=0.f;
    #pragma unroll
    for (int g = 0; g < 4; ++g){ float4 v = pool4[g][t]; A0+=v.x; A1+=v.y; V0+=v.z; V1+=v.w; }
    red4[0][t] = make_float2(V0, V1);
    float mx = fmaxf(A0, A1);
    att0 = fexp(A0 - mx); att1 = fexp(A1 - mx);
    rsv = frcp(att0 + att1);
  }
  __syncthreads();   // B15

  if (t < 128){
    float r0, r1;
    if (t < 64){ r0 = red4[0][2*t].x;     r1 = red4[0][2*t+1].x; }
    else       { r0 = red4[0][2*t-128].y; r1 = red4[0][2*t-127].y; }
    hq[t] = (reluf(r0)*att0 + reluf(r1)*att1)*rsv;
  }
  if (t >= 192 && t < 256) hq[128 + (t - 192)] = ips[t - 192];
  __syncthreads();   // B16

  // ---- MHA ----
  const float wq = mha_in_w[0], wk = mha_in_w[1], wvv_ = mha_in_w[2];
  const float bq = mha_in_b[0], bk = mha_in_b[1], bv = mha_in_b[2];
  const float wo = mha_out_w[0], bo = mha_out_b[0];
  if (t < 192){
    float hv_ = hq[t];
    kv[t] = make_float2(__fmaf_rn(hv_, wk, bk), __fmaf_rn(hv_, wvv_, bv));
  }
  __syncthreads();   // B17

  if (t < 64){
    float k0 = kv[t].x, k1 = kv[t+64].x, k2 = kv[t+128].x;
    float mx = fmaxf(fmaxf(k0, k1), k2);
    float mn = fminf(fminf(k0, k1), k2);
    #pragma unroll
    for (int off = 32; off; off >>= 1){
      mx = fmaxf(mx, __shfl_xor(mx, off));
      mn = fminf(mn, __shfl_xor(mn, off));
    }
    if (t == 0){ sred[3] = mx; sred[4] = mn; }
  }
  __syncthreads();   // B18

  if (t < 384){
    const int half = (t >= 192), tt = t - half*192;
    float qi = __fmaf_rn(hq[tt], wq, bq);
    float mx = (qi >= 0.f) ? qi*sred[3] : qi*sred[4];
    const float qi2 = qi*L2E, mx2 = mx*L2E;
    float den = 0.f, num = 0.f;
    const int j0 = half*96;
    #pragma unroll 8
    for (int jj = 0; jj < 96; ++jj){
      float2 K = kv[j0 + jj];
      float e = __builtin_amdgcn_exp2f(__fmaf_rn(qi2, K.x, -mx2));
      den += e; num = __fmaf_rn(e, K.y, num);
    }
    pden[half][tt] = den; pnum[half][tt] = num;
  }
  __syncthreads();   // B19

  if (t < 192){
    float den = pden[0][t] + pden[1][t];
    float num = pnum[0][t] + pnum[1][t];
    h2s[t] = __fmaf_rn(num*frcp(den), wo, bo) + hq[t];
  }
  __syncthreads();   // B20

  // ---- fl1: 192->128 (4-way split) ----
  {
    const int n = t & 127, qtr = t >> 7;
    float acc = 0.f;
    const int i0 = qtr*48;
    #pragma unroll 8
    for (int k = 0; k < 48; ++k){
      int i = i0 + k;
      acc = __fmaf_rn(h2s[i], fl1_w[i*128 + n], acc);
    }
    red4[qtr][n].x = acc;
  }
  __syncthreads();   // B21

  if (t < 128) rho_s[t] = reluf(red4[0][t].x + red4[1][t].x + red4[2][t].x + red4[3][t].x + fl1_b[t]);
  __syncthreads();   // B22

  // ---- fl2: 128->32 (4-way split) ----
  if (t < 128){
    const int n = t & 31, seg = t >> 5;
    float p = 0.f;
    #pragma unroll 8
    for (int k = 0; k < 32; ++k){
      int i = seg*32 + k;
      p = __fmaf_rn(rho_s[i], fl2_w[i*32 + n], p);
    }
    eAs[t] = p;
  }
  __syncthreads();   // B23

  if (t < 32) hm[t] = tanh_n(eAs[t] + eAs[t+32] + eAs[t+64] + eAs[t+96] + fl2_b[t]);
  __syncthreads();   // B24

  // ---- fl3: 32->1 ----
  if (t < 64){
    float p = (t < 32) ? hm[t]*fl3_w[t] : 0.f;
    #pragma unroll
    for (int off = 32; off; off >>= 1) p += __shfl_xor(p, off);
    if (t == 0) out[b] = reluf(p + fl3_b[0]);
  }
}

extern "C" void kernel_launch(void* const* d_in, const int* in_sizes, int n_in,
                              void* d_out, int out_size, void* d_ws, size_t ws_size,
                              hipStream_t stream) {
  const int*   adj    = (const int*)  d_in[0];
  const float* feat   = (const float*)d_in[1];
  const float* timei  = (const float*)d_in[2];
  const float* ipop   = (const float*)d_in[3];
  const float* W1     = (const float*)d_in[4];
  const float* a1     = (const float*)d_in[5];
  const float* W2     = (const float*)d_in[6];
  const float* a2     = (const float*)d_in[7];
  const float* Weight = (const float*)d_in[8];
  const float* Wv     = (const float*)d_in[9];
  const float* wih0   = (const float*)d_in[10];
  const float* whh0   = (const float*)d_in[11];
  const float* bih0   = (const float*)d_in[12];
  const float* bhh0   = (const float*)d_in[13];
  const float* wih1   = (const float*)d_in[14];
  const float* whh1   = (const float*)d_in[15];
  const float* bih1   = (const float*)d_in[16];
  const float* bhh1   = (const float*)d_in[17];
  const float* mha_in_w  = (const float*)d_in[18];
  const float* mha_in_b  = (const float*)d_in[19];
  const float* mha_out_w = (const float*)d_in[20];
  const float* mha_out_b = (const float*)d_in[21];
  const float* fl1_w = (const float*)d_in[22];
  const float* fl1_b = (const float*)d_in[23];
  const float* fl2_w = (const float*)d_in[24];
  const float* fl2_b = (const float*)d_in[25];
  const float* fl3_w = (const float*)d_in[26];
  const float* fl3_b = (const float*)d_in[27];

  fused_kernel<<<512, 512, 0, stream>>>(adj, feat, timei, Weight, Wv,
                                        W1, a1, W2, a2, ipop,
                                        wih0, whh0, bih0, bhh0,
                                        wih1, whh1, bih1, bhh1,
                                        mha_in_w, mha_in_b, mha_out_w, mha_out_b,
                                        fl1_w, fl1_b, fl2_w, fl2_b, fl3_w, fl3_b,
                                        (float*)d_out);
}